// Round 4
// baseline (236.241 us; speedup 1.0000x reference)
//
#include <hip/hip_runtime.h>
#include <hip/hip_bf16.h>
#include <cstdint>
#include <cstddef>

// JacobiKANLinear: DEGREE=5, A=B=1.0. Inputs fp32, output fp32 (HW-verified r1/r2/r5).
// v5: PRODUCER-CONSUMER wave specialization. r3 showed MFMA-issue and expansion
// VALU serialize when every wave does both (5625 cyc/step/SIMD = 1862 MFMA +
// 2600 VALU + 1150 wait). Fix: waves 0-3 = pure MFMA consumers, waves 4-7 =
// expansion+staging producers; pipes co-issue per m114. One barrier per step.
#define BATCH   8192
#define IN_F    1024
#define OUT_F   1024
#define KAUG    (6 * 1024)   // k = i*6 + j ; j=0 -> base weight (silu), j=1..5 -> P_j
#define NSTEP   64           // K-steps: 6144 / 96

typedef __bf16 bf16x8 __attribute__((ext_vector_type(8)));
typedef float  f32x4  __attribute__((ext_vector_type(4)));

// Workspace layout (bytes), ~12.6 MB:
static constexpr size_t WAUG_B    = (size_t)OUT_F * KAUG * 2;        // 12,582,912
static constexpr size_t BIAS2_OFF = WAUG_B;                          // 4 KB f32

// Jacobi recurrence for A=B=1 (beta_n = 0): P_k = (a_k t)P_{k-1} - (b_k)P_{k-2}
constexpr float JA[4] = {64.f/120.f, 180.f/336.f, 384.f/720.f, 700.f/1320.f};
constexpr float JB[4] = {48.f/120.f, 144.f/336.f, 320.f/720.f, 600.f/1320.f};

__device__ __forceinline__ unsigned short f2bf(float f)
{
    __hip_bfloat16 h = __float2bfloat16(f);
    return *(unsigned short*)&h;
}
__device__ __forceinline__ unsigned pack2(float lo, float hi)   // RNE (prep path)
{
    return (unsigned)f2bf(lo) | ((unsigned)f2bf(hi) << 16);
}
// Fast packed conversion: D[15:0]=bf16(lo), D[31:16]=bf16(hi).
__device__ __forceinline__ unsigned cvt_pk(float lo, float hi)
{
    unsigned r;
    asm("v_cvt_pk_bf16_f32 %0, %1, %2" : "=v"(r) : "v"(lo), "v"(hi));
    return r;
}

// ---------------- prep: weights + bias fold only (1024 blocks) ----------------
__global__ void prep_w(const float* __restrict__ W,
                       const float* __restrict__ C,
                       const float* __restrict__ bias,
                       __hip_bfloat16* __restrict__ Waug,
                       float* __restrict__ bias2)
{
    const int o = blockIdx.x;
    const int tid = threadIdx.x;
    const int i = tid * 4;

    const float4 wv = *(const float4*)(W + (size_t)o * IN_F + i);
    const float w4[4] = {wv.x, wv.y, wv.z, wv.w};

    float f[24];   // 24 consecutive floats = C[o][i..i+3][0..5]
    const float2* cp = (const float2*)(C + ((size_t)o * IN_F + i) * 6);
#pragma unroll
    for (int q = 0; q < 12; ++q) { const float2 v = cp[q]; f[q * 2] = v.x; f[q * 2 + 1] = v.y; }

    unsigned pk[12];
#pragma unroll
    for (int q = 0; q < 4; ++q) {
        pk[q * 3 + 0] = pack2(w4[q],        f[q * 6 + 1]);
        pk[q * 3 + 1] = pack2(f[q * 6 + 2], f[q * 6 + 3]);
        pk[q * 3 + 2] = pack2(f[q * 6 + 4], f[q * 6 + 5]);
    }
    uint4* dst = (uint4*)(Waug + (size_t)o * KAUG + (size_t)tid * 24);  // 48 B/thread
    dst[0] = make_uint4(pk[0], pk[1], pk[2],  pk[3]);
    dst[1] = make_uint4(pk[4], pk[5], pk[6],  pk[7]);
    dst[2] = make_uint4(pk[8], pk[9], pk[10], pk[11]);

    float s = f[0] + f[6] + f[12] + f[18];        // j=0 terms
#pragma unroll
    for (int off = 32; off > 0; off >>= 1) s += __shfl_down(s, off, 64);
    __shared__ float red[4];
    if ((tid & 63) == 0) red[tid >> 6] = s;
    __syncthreads();
    if (tid == 0) bias2[o] = bias[o] + red[0] + red[1] + red[2] + red[3];
}

// ---------------- fused GEMM, producer-consumer ----------------
// 128x128 tile, BK=96 (16 inputs), 512 threads.
//   waves 0-3 (consumers): 2x2 wave grid, 64x64 out each, acc[4][4], 48 MFMA/step.
//   waves 4-7 (producers): expand 128 rows x 16 inputs -> As[(t+1)&1] (bf16),
//                          stage B(t+2) -> Bs[(t+2)%3] via global_load_lds,
//                          prefetch x(t+2) to regs.
// LDS: As 2 x 24 KB + Bs 3 x 24 KB = 120 KB -> 1 block/CU, 8 waves =
// 1 consumer + 1 producer per SIMD (round-robin wave placement) -> MFMA pipe
// and expansion VALU co-issue (m114).
// Sync: ONE barrier/step. Producers: s_waitcnt vmcnt(0) lgkmcnt(0) before it —
// nearly free because B/x loads were issued a full expansion (~600+ cyc) earlier
// and are 2 intervals ahead of consumption. Consumers: raw s_barrier (their
// ds_reads complete before MFMA use; data read next interval is in a buffer
// written the previous interval).
// Buffer discipline (reader iter t / writer iter):
//   As[t&1]  read at t ; written at t-1 (producer target (t'+1)&1, t'=t-1) OK
//   Bs[t%3]  read at t ; loads issued at t-2, landed by end of t-1 (vmcnt(0)) OK
//   overwrite of each buffer starts exactly one barrier after its last read. OK
__device__ __forceinline__ void async_load16(const void* g, void* l)
{
    __builtin_amdgcn_global_load_lds(
        (const __attribute__((address_space(1))) void*)g,
        (__attribute__((address_space(3))) void*)l,
        16, 0, 0);
}

#define AS_B    24576                 // per As buffer (128 rows x 192 B)
#define BS_B    24576                 // per Bs buffer
#define SMEM_B  (2 * AS_B + 3 * BS_B) // 122880

// Expand 8 inputs -> [silu, P1..P5] bf16, write 96 B at dst (~25 VALU/elem).
__device__ __forceinline__ void expand8(const float4 x0, const float4 x1, char* dst)
{
    const float xs[8] = {x0.x, x0.y, x0.z, x0.w, x1.x, x1.y, x1.z, x1.w};
    unsigned pk[24];
#pragma unroll
    for (int e = 0; e < 8; ++e) {
        const float x  = xs[e];
        const float v  = __expf(fminf(-x, 43.f));                        // e^-x
        const float sg = __builtin_amdgcn_rcpf(1.f + v);
        const float s  = x * sg;                                         // silu
        const float u  = v * v;                                          // e^-2x
        const float tt = (1.f - u) * __builtin_amdgcn_rcpf(1.f + u);     // tanh
        const float p1 = 2.f * tt;
        const float p2 = JA[0] * tt * p1 - JB[0];
        const float p3 = JA[1] * tt * p2 - JB[1] * p1;
        const float p4 = JA[2] * tt * p3 - JB[2] * p2;
        const float p5 = JA[3] * tt * p4 - JB[3] * p3;
        pk[e * 3 + 0] = cvt_pk(s,  p1);
        pk[e * 3 + 1] = cvt_pk(p2, p3);
        pk[e * 3 + 2] = cvt_pk(p4, p5);
    }
#pragma unroll
    for (int j = 0; j < 6; ++j)
        *(uint4*)(dst + j * 16) = make_uint4(pk[j * 4], pk[j * 4 + 1],
                                             pk[j * 4 + 2], pk[j * 4 + 3]);
}

__global__ __launch_bounds__(512, 2)
void gemm_kan(const float* __restrict__ X,
              const __hip_bfloat16* __restrict__ Waug,
              const float* __restrict__ bias2,
              float* __restrict__ out)
{
    extern __shared__ __align__(16) char smem[];   // [As0 | As1 | Bs0 | Bs1 | Bs2]

    const int tid  = threadIdx.x;
    const int lane = tid & 63;
    const int wave = tid >> 6;
    const int mBase = blockIdx.x * 128;            // M fastest -> XCD = bx % 8
    const int nBase = blockIdx.y * 128;

    if (wave < 4) {
        // ================= CONSUMERS =================
        const int wm = wave & 1, wn = wave >> 1;
        const int quad = lane >> 4, mr = lane & 15;
        const int aoff = (wm * 64 + mr) * 12 + quad;      // 16B units within As buf
        const int boff = (wn * 64 + mr) * 12 + quad;      // 16B units within Bs buf
        const int BS0  = 2 * (AS_B / 16);

        f32x4 acc[4][4] = {};
        asm volatile("s_barrier" ::: "memory");           // matches producer prologue

        int ab = 0, bb = 0;
        const bf16x8* V = (const bf16x8*)smem;
#pragma unroll 1
        for (int t = 0; t < NSTEP; ++t) {
            const int abase = ab * (AS_B / 16) + aoff;
            const int bbase = BS0 + bb * (BS_B / 16) + boff;
            __builtin_amdgcn_s_setprio(1);
#pragma unroll
            for (int kc = 0; kc < 3; ++kc) {
                bf16x8 a[4], b[4];
#pragma unroll
                for (int t4 = 0; t4 < 4; ++t4) a[t4] = V[abase + t4 * 192 + kc * 4];
#pragma unroll
                for (int t4 = 0; t4 < 4; ++t4) b[t4] = V[bbase + t4 * 192 + kc * 4];
#pragma unroll
                for (int i = 0; i < 4; ++i)
#pragma unroll
                    for (int jj = 0; jj < 4; ++jj)
                        acc[i][jj] = __builtin_amdgcn_mfma_f32_16x16x32_bf16(
                            a[i], b[jj], acc[i][jj], 0, 0, 0);
            }
            __builtin_amdgcn_s_setprio(0);
            asm volatile("s_barrier" ::: "memory");
            ab ^= 1; bb = (bb == 2) ? 0 : bb + 1;
        }

        // ---- epilogue (m89-verified C/D map: row_in_16 = quad*4+r, col = mr) ----
#pragma unroll
        for (int i = 0; i < 4; ++i) {
#pragma unroll
            for (int jj = 0; jj < 4; ++jj) {
                const int col = nBase + wn * 64 + jj * 16 + mr;
                const float b2 = bias2[col];
#pragma unroll
                for (int r = 0; r < 4; ++r) {
                    const int row = mBase + wm * 64 + i * 16 + quad * 4 + r;
                    out[(size_t)row * OUT_F + col] = acc[i][jj][r] + b2;
                }
            }
        }
    } else {
        // ================= PRODUCERS =================
        const int ptid = tid - 256;                       // 0..255
        const int pw   = wave - 4;                        // 0..3
        const float* gx = X + (size_t)(mBase + (ptid >> 1)) * IN_F + (ptid & 1) * 8;
        char* const awp = smem + (ptid >> 1) * 192 + (ptid & 1) * 96;

        const __hip_bfloat16* gB[6]; int lB[6];
#pragma unroll
        for (int q = 0; q < 6; ++q) {
            const int ci = (q * 4 + pw) * 64 + lane;      // 16B-chunk idx in 24 KB tile
            const int br = ci / 12, bc = ci - br * 12;
            gB[q] = Waug + (size_t)(nBase + br) * KAUG + bc * 8;
            lB[q] = 2 * AS_B + (q * 4 + pw) * 1024;       // + lane*16 added by HW
        }

        // ---- prologue: x(0),B(0),x(1),B(1); expand(0) -> As[0] ----
        float4 xc0 = *(const float4*)(gx);
        float4 xc1 = *(const float4*)(gx + 4);
#pragma unroll
        for (int q = 0; q < 6; ++q) async_load16(gB[q], smem + lB[q]);            // B(0)->Bs0
        float4 xn0 = *(const float4*)(gx + 16);
        float4 xn1 = *(const float4*)(gx + 20);
#pragma unroll
        for (int q = 0; q < 6; ++q) async_load16(gB[q] + 96, smem + lB[q] + BS_B); // B(1)->Bs1
        expand8(xc0, xc1, awp);                                                    // As[0]
        asm volatile("s_waitcnt vmcnt(0) lgkmcnt(0)" ::: "memory");
        asm volatile("s_barrier" ::: "memory");

        int b3 = 2;                                       // Bs target = (t+2)%3
#pragma unroll 1
        for (int t = 0; t < NSTEP; ++t) {
            xc0 = xn0; xc1 = xn1;                         // x(t+1) becomes current
            if (t + 2 < NSTEP) {
                xn0 = *(const float4*)(gx + (size_t)(t + 2) * 16);
                xn1 = *(const float4*)(gx + (size_t)(t + 2) * 16 + 4);
#pragma unroll
                for (int q = 0; q < 6; ++q)
                    async_load16(gB[q] + (size_t)(t + 2) * 96, smem + lB[q] + b3 * BS_B);
                b3 = (b3 == 2) ? 0 : b3 + 1;
            }
            if (t + 1 < NSTEP) {
                expand8(xc0, xc1, awp + ((t + 1) & 1) * AS_B);
            }
            // loads above aged by the whole expansion (~600+ cyc) -> near-free drain;
            // guarantees B(t+1)/As(t+1) ready for consumers' next interval.
            asm volatile("s_waitcnt vmcnt(0) lgkmcnt(0)" ::: "memory");
            asm volatile("s_barrier" ::: "memory");
        }
    }
}

// ---------------- launch ----------------

extern "C" void kernel_launch(void* const* d_in, const int* in_sizes, int n_in,
                              void* d_out, int out_size, void* d_ws, size_t ws_size,
                              hipStream_t stream)
{
    (void)out_size; (void)ws_size;
    const float* x    = (const float*)d_in[0];
    const float* W    = (const float*)d_in[1];
    const float* C    = (const float*)d_in[2];
    const float* bias = (const float*)d_in[3];
    for (int i = 0; i < n_in; ++i) {
        if      (in_sizes[i] == BATCH * IN_F)     x    = (const float*)d_in[i];
        else if (in_sizes[i] == OUT_F * IN_F)     W    = (const float*)d_in[i];
        else if (in_sizes[i] == OUT_F * IN_F * 6) C    = (const float*)d_in[i];
        else if (in_sizes[i] == OUT_F)            bias = (const float*)d_in[i];
    }
    float* out = (float*)d_out;
    char* ws = (char*)d_ws;
    __hip_bfloat16* Waug  = (__hip_bfloat16*)ws;
    float*          bias2 = (float*)(ws + BIAS2_OFF);

    // 120 KB dynamic LDS (> 64 KB default): opt in once (144 KB proven r1).
    static bool smem_attr_done = false;
    if (!smem_attr_done) {
        (void)hipFuncSetAttribute((const void*)gemm_kan,
                                  hipFuncAttributeMaxDynamicSharedMemorySize,
                                  SMEM_B);
        smem_attr_done = true;
    }

    prep_w<<<dim3(OUT_F), dim3(256), 0, stream>>>(W, C, bias, Waug, bias2);
    gemm_kan<<<dim3(BATCH / 128, OUT_F / 128), dim3(512), SMEM_B, stream>>>(
        x, Waug, bias2, out);
}

// Round 5
// 219.828 us; speedup vs baseline: 1.0747x; 1.0747x over previous
//
#include <hip/hip_runtime.h>
#include <hip/hip_bf16.h>
#include <cstdint>
#include <cstddef>

// JacobiKANLinear: DEGREE=5, A=B=1.0. Inputs fp32, output fp32 (HW-verified r1/r2/r5).
// v6: gemm = r3's v4 (150 us, best measured). prep_w rewritten with LDS-staged
// coalescing: r2-r4 data shows ~60 us hidden in prep_w's 96B-stride C gather
// (12x cache-line request amplification) + 48B-stride scatter stores.
#define BATCH   8192
#define IN_F    1024
#define OUT_F   1024
#define KAUG    (6 * 1024)   // k = i*6 + j ; j=0 -> base weight (silu), j=1..5 -> P_j
#define NSTEP   64           // K-steps: 6144 / 96

typedef __bf16 bf16x8 __attribute__((ext_vector_type(8)));
typedef float  f32x4  __attribute__((ext_vector_type(4)));

// Workspace layout (bytes), ~12.6 MB:
static constexpr size_t WAUG_B    = (size_t)OUT_F * KAUG * 2;        // 12,582,912
static constexpr size_t BIAS2_OFF = WAUG_B;                          // 4 KB f32

// Jacobi recurrence for A=B=1 (beta_n = 0): P_k = (a_k t)P_{k-1} - (b_k)P_{k-2}
constexpr float JA[4] = {64.f/120.f, 180.f/336.f, 384.f/720.f, 700.f/1320.f};
constexpr float JB[4] = {48.f/120.f, 144.f/336.f, 320.f/720.f, 600.f/1320.f};

__device__ __forceinline__ unsigned short f2bf(float f)
{
    __hip_bfloat16 h = __float2bfloat16(f);
    return *(unsigned short*)&h;
}
__device__ __forceinline__ unsigned pack2(float lo, float hi)   // RNE (prep path)
{
    return (unsigned)f2bf(lo) | ((unsigned)f2bf(hi) << 16);
}
// Fast packed conversion: D[15:0]=bf16(lo), D[31:16]=bf16(hi).
__device__ __forceinline__ unsigned cvt_pk(float lo, float hi)
{
    unsigned r;
    asm("v_cvt_pk_bf16_f32 %0, %1, %2" : "=v"(r) : "v"(lo), "v"(hi));
    return r;
}

// ---------------- prep: weights + bias fold only (1024 blocks) ----------------
// Waug[o][i*6 + 0] = bf16(W[o][i]) ; Waug[o][i*6 + j] = bf16(C[o][i][j]), j=1..5.
// bias2[o] = bias[o] + sum_i C[o][i][0]  (P0 == 1 fold).
// v6: ALL global traffic coalesced via LDS staging. C-row (24 KB) loaded with
// consecutive-lane float4s -> LDS; per-thread 96B gathers hit LDS (bank
// conflicts negligible: ~24 MB total LDS volume). Packed output re-staged in
// LDS and stored with consecutive-lane uint4s.
__global__ void prep_w(const float* __restrict__ W,
                       const float* __restrict__ C,
                       const float* __restrict__ bias,
                       __hip_bfloat16* __restrict__ Waug,
                       float* __restrict__ bias2)
{
    const int o = blockIdx.x;
    const int tid = threadIdx.x;

    __shared__ __align__(16) float cs[IN_F * 6];   // 24 KB
    __shared__ float red[4];

    // ---- coalesced C-row load: 6 x float4 per thread, lane-consecutive ----
    const float4* C4  = (const float4*)(C + (size_t)o * IN_F * 6);
    float4*       cs4 = (float4*)cs;
#pragma unroll
    for (int k = 0; k < 6; ++k) cs4[tid + k * 256] = C4[tid + k * 256];

    // W row: lane-consecutive float4 (already coalesced)
    const float4 wv = ((const float4*)(W + (size_t)o * IN_F))[tid];
    const float w4[4] = {wv.x, wv.y, wv.z, wv.w};

    __syncthreads();

    // ---- per-thread gather from LDS: 24 floats = C[o][i..i+3][0..5] ----
    float f[24];
#pragma unroll
    for (int q = 0; q < 6; ++q) {
        const float4 v = cs4[tid * 6 + q];
        f[q * 4 + 0] = v.x; f[q * 4 + 1] = v.y; f[q * 4 + 2] = v.z; f[q * 4 + 3] = v.w;
    }

    unsigned pk[12];
#pragma unroll
    for (int q = 0; q < 4; ++q) {
        pk[q * 3 + 0] = pack2(w4[q],        f[q * 6 + 1]);
        pk[q * 3 + 1] = pack2(f[q * 6 + 2], f[q * 6 + 3]);
        pk[q * 3 + 2] = pack2(f[q * 6 + 4], f[q * 6 + 5]);
    }

    float s = f[0] + f[6] + f[12] + f[18];        // j=0 terms
#pragma unroll
    for (int off = 32; off > 0; off >>= 1) s += __shfl_down(s, off, 64);
    if ((tid & 63) == 0) red[tid >> 6] = s;

    __syncthreads();                               // everyone done reading cs
    // ---- restage packed row in LDS (768 uint4 = 12 KB, reuse cs) ----
    uint4* csU = (uint4*)cs;
    csU[tid * 3 + 0] = make_uint4(pk[0], pk[1], pk[2],  pk[3]);
    csU[tid * 3 + 1] = make_uint4(pk[4], pk[5], pk[6],  pk[7]);
    csU[tid * 3 + 2] = make_uint4(pk[8], pk[9], pk[10], pk[11]);
    __syncthreads();

    // ---- coalesced store: 3 x uint4 per thread, lane-consecutive ----
    uint4* out4 = (uint4*)(Waug + (size_t)o * KAUG);
#pragma unroll
    for (int k = 0; k < 3; ++k) out4[tid + k * 256] = csU[tid + k * 256];

    if (tid == 0) bias2[o] = bias[o] + red[0] + red[1] + red[2] + red[3];
}

// ---------------- fused GEMM (r3/v4, verbatim: 150 us measured) ----------------
// 128x128 tile, BK=96 (16 inputs), 256 threads (2x2 waves, 64x64/wave).
// A: computed on the fly from x (fp32) -> regs -> ds_write bf16 (single buffer).
// B: Waug via global_load_lds, double-buffered, issued at top of compute so the
//    __syncthreads vmcnt drain sees loads aged by a full compute phase (r0-proven).
// LDS: As 24 KB + Bs 2x24 KB = 72 KB -> 2 blocks/CU (cross-block overlap, m114).
__device__ __forceinline__ void async_load16(const void* g, void* l)
{
    __builtin_amdgcn_global_load_lds(
        (const __attribute__((address_space(1))) void*)g,
        (__attribute__((address_space(3))) void*)l,
        16, 0, 0);
}

#define AS_B    24576                 // As bytes (128 rows x 192 B)
#define BS_B    24576                 // per-buffer Bs bytes
#define SMEM_B  (AS_B + 2 * BS_B)     // 73728

__global__ __launch_bounds__(256, 2)
void gemm_kan(const float* __restrict__ X,
              const __hip_bfloat16* __restrict__ Waug,
              const float* __restrict__ bias2,
              float* __restrict__ out)
{
    extern __shared__ __align__(16) char smem[];   // [As 24576 | Bs0 24576 | Bs1 24576]

    const int tid  = threadIdx.x;
    const int lane = tid & 63;
    const int wave = tid >> 6;
    const int wm = wave & 1, wn = wave >> 1;
    const int mBase = blockIdx.x * 128;            // M fastest -> XCD = bx % 8
    const int nBase = blockIdx.y * 128;

    // ---- x source for expansion: row r = tid>>1, inputs (tid&1)*8 .. +7 ----
    const float* gx = X + (size_t)(mBase + (tid >> 1)) * IN_F + (tid & 1) * 8;
    char* const aw = smem + (tid >> 1) * 192 + (tid & 1) * 96;   // thread's 96 B in As

    // ---- B staging: 6 x 16B chunks per thread; LDS dest wave-uniform base ----
    const __hip_bfloat16* gB[6]; int lB[6];
#pragma unroll
    for (int q = 0; q < 6; ++q) {
        const int ci = (q * 4 + wave) * 64 + lane;   // 16B-chunk index in 24 KB tile
        const int br = ci / 12, bc = ci - br * 12;   // row 0..127, chunk 0..11
        gB[q] = Waug + (size_t)(nBase + br) * KAUG + bc * 8;
        lB[q] = AS_B + (q * 4 + wave) * 1024;        // + lane*16 added by HW
    }

    // ---- fragment offsets (16B-vector units) ----
    const int quad = lane >> 4, mr = lane & 15;
    const int aoff = (wm * 64 + mr) * 12 + quad;
    const int boff = (AS_B / 16) + (wn * 64 + mr) * 12 + quad;

    f32x4 acc[4][4] = {};

    // ---- prologue: x(0) to regs; B-stage(0) -> buf0 ----
    float4 xc0 = *(const float4*)(gx);
    float4 xc1 = *(const float4*)(gx + 4);
#pragma unroll
    for (int q = 0; q < 6; ++q) async_load16(gB[q], smem + lB[q]);

#pragma unroll 1
    for (int t = 0; t < NSTEP; ++t) {
        // ---- expand 8 inputs -> 48 bf16 (regs only) ----
        const float xs[8] = {xc0.x, xc0.y, xc0.z, xc0.w, xc1.x, xc1.y, xc1.z, xc1.w};
        unsigned pk[24];
#pragma unroll
        for (int e = 0; e < 8; ++e) {
            const float x  = xs[e];
            // v = e^-x, clamped so u = v*v stays finite (x <= -43: sig->0, t->-1)
            const float v  = __expf(fminf(-x, 43.f));
            const float sg = __builtin_amdgcn_rcpf(1.f + v);
            const float s  = x * sg;                  // silu(x) = x * sigmoid(x)
            const float u  = v * v;                   // e^-2x
            const float tt = (1.f - u) * __builtin_amdgcn_rcpf(1.f + u);   // tanh(x)
            const float p1 = 2.f * tt;
            const float p2 = JA[0] * tt * p1 - JB[0];
            const float p3 = JA[1] * tt * p2 - JB[1] * p1;
            const float p4 = JA[2] * tt * p3 - JB[2] * p2;
            const float p5 = JA[3] * tt * p4 - JB[3] * p3;
            pk[e * 3 + 0] = cvt_pk(s,  p1);
            pk[e * 3 + 1] = cvt_pk(p2, p3);
            pk[e * 3 + 2] = cvt_pk(p4, p5);
        }
        __syncthreads();               // all waves done reading As(t-1); drains aged vmem
        // ---- write As(t) ----
#pragma unroll
        for (int j = 0; j < 6; ++j)
            *(uint4*)(aw + j * 16) = make_uint4(pk[j * 4], pk[j * 4 + 1],
                                                pk[j * 4 + 2], pk[j * 4 + 3]);
        __syncthreads();               // As(t) visible (lgkm drain; no young vmem)

        // ---- issue next-step loads FIRST: they age through the compute phase ----
        if (t + 1 < NSTEP) {
            char* const bs = smem + ((t + 1) & 1) * BS_B;
#pragma unroll
            for (int q = 0; q < 6; ++q) async_load16(gB[q] + (t + 1) * 96, bs + lB[q]);
            xc0 = *(const float4*)(gx + (t + 1) * 16);
            xc1 = *(const float4*)(gx + (t + 1) * 16 + 4);
        }

        // ---- compute: 3 k-chunks x 16 MFMA from As + Bs[t&1] ----
        const bf16x8* V = (const bf16x8*)smem;
        const int bo = boff + (t & 1) * (BS_B / 16);
#pragma unroll
        for (int kc = 0; kc < 3; ++kc) {
            bf16x8 a[4], b[4];
#pragma unroll
            for (int t4 = 0; t4 < 4; ++t4) a[t4] = V[aoff + t4 * 192 + kc * 4];
#pragma unroll
            for (int t4 = 0; t4 < 4; ++t4) b[t4] = V[bo + t4 * 192 + kc * 4];
#pragma unroll
            for (int i = 0; i < 4; ++i)
#pragma unroll
                for (int jj = 0; jj < 4; ++jj)
                    acc[i][jj] = __builtin_amdgcn_mfma_f32_16x16x32_bf16(a[i], b[jj], acc[i][jj], 0, 0, 0);
        }
    }

    // ---- direct-store epilogue; C/D map hardcoded (m89-verified: row_in_16 =
    // quad*4+r, col = mr — matches the probe this session measured every run) ----
#pragma unroll
    for (int i = 0; i < 4; ++i) {
#pragma unroll
        for (int jj = 0; jj < 4; ++jj) {
            const int col = nBase + wn * 64 + jj * 16 + mr;
            const float b2 = bias2[col];
#pragma unroll
            for (int r = 0; r < 4; ++r) {
                const int row = mBase + wm * 64 + i * 16 + quad * 4 + r;
                out[(size_t)row * OUT_F + col] = acc[i][jj][r] + b2;
            }
        }
    }
}

// ---------------- launch ----------------

extern "C" void kernel_launch(void* const* d_in, const int* in_sizes, int n_in,
                              void* d_out, int out_size, void* d_ws, size_t ws_size,
                              hipStream_t stream)
{
    (void)out_size; (void)ws_size;
    const float* x    = (const float*)d_in[0];
    const float* W    = (const float*)d_in[1];
    const float* C    = (const float*)d_in[2];
    const float* bias = (const float*)d_in[3];
    for (int i = 0; i < n_in; ++i) {
        if      (in_sizes[i] == BATCH * IN_F)     x    = (const float*)d_in[i];
        else if (in_sizes[i] == OUT_F * IN_F)     W    = (const float*)d_in[i];
        else if (in_sizes[i] == OUT_F * IN_F * 6) C    = (const float*)d_in[i];
        else if (in_sizes[i] == OUT_F)            bias = (const float*)d_in[i];
    }
    float* out = (float*)d_out;
    char* ws = (char*)d_ws;
    __hip_bfloat16* Waug  = (__hip_bfloat16*)ws;
    float*          bias2 = (float*)(ws + BIAS2_OFF);

    // 72 KB dynamic LDS (> 64 KB default): opt in once (proven path, r1).
    static bool smem_attr_done = false;
    if (!smem_attr_done) {
        (void)hipFuncSetAttribute((const void*)gemm_kan,
                                  hipFuncAttributeMaxDynamicSharedMemorySize,
                                  SMEM_B);
        smem_attr_done = true;
    }

    prep_w<<<dim3(OUT_F), dim3(256), 0, stream>>>(W, C, bias, Waug, bias2);
    gemm_kan<<<dim3(BATCH / 128, OUT_F / 128), dim3(256), SMEM_B, stream>>>(
        x, Waug, bias2, out);
}